// Round 1
// baseline (1548.217 us; speedup 1.0000x reference)
//
#include <hip/hip_runtime.h>

#define NNODES 100000
#define NEDGES 1600000
#define FIN 128
#define FH 64
#define FOUT 32
#define NGRAPH 128
#define EPSV 1e-5f

// ---------------- degree / normalization ----------------

__global__ void k_init_deg(float* __restrict__ deg) {
  int i = blockIdx.x * blockDim.x + threadIdx.x;
  if (i < NNODES) deg[i] = 1.0f;  // self-loop contributes 1
}

__global__ void k_deg_accum(const int* __restrict__ dst, float* __restrict__ deg) {
  int i = blockIdx.x * blockDim.x + threadIdx.x;
  if (i < NEDGES) atomicAdd(&deg[dst[i]], 1.0f);
}

__global__ void k_rsqrt(float* __restrict__ deg) {
  int i = blockIdx.x * blockDim.x + threadIdx.x;
  if (i < NNODES) deg[i] = rsqrtf(deg[i]);  // deg >= 1 always
}

// ---------------- skinny GEMM: out[N x 64] = act(A[N x K]) @ W[K x 64] -------
// One thread per row, 64 fp32 accumulators. W accesses are wave-uniform.
// If BN: input activation = relu(a * sc[k] + sh[k]) (fused BN+ReLU on load).

template <int K, bool BN>
__global__ void k_gemm(const float* __restrict__ A, const float* __restrict__ W,
                       const float* __restrict__ sc, const float* __restrict__ sh,
                       float* __restrict__ out) {
  int row = blockIdx.x * blockDim.x + threadIdx.x;
  if (row >= NNODES) return;
  float acc[FH];
#pragma unroll
  for (int j = 0; j < FH; ++j) acc[j] = 0.0f;
  const float* a = A + (long long)row * K;
  for (int k = 0; k < K; k += 4) {
    float4 x4 = *(const float4*)(a + k);
    float xs[4] = {x4.x, x4.y, x4.z, x4.w};
#pragma unroll
    for (int kk = 0; kk < 4; ++kk) {
      float xv = xs[kk];
      if (BN) {
        xv = fmaf(xv, sc[k + kk], sh[k + kk]);
        xv = fmaxf(xv, 0.0f);
      }
      const float* wr = W + (k + kk) * FH;
#pragma unroll
      for (int j = 0; j < FH; ++j) acc[j] = fmaf(xv, wr[j], acc[j]);
    }
  }
  float* o = out + (long long)row * FH;
#pragma unroll
  for (int j = 0; j < FH; j += 4) {
    float4 v = {acc[j], acc[j + 1], acc[j + 2], acc[j + 3]};
    *(float4*)(o + j) = v;
  }
}

// ---------------- message passing: out[dst] += h[src] * dis[src]*dis[dst] ----
// One wave per edge; lane = feature. Edges [0,E) are real, [E, E+N) self-loops.

__global__ void k_scatter(const float* __restrict__ h, const int* __restrict__ src,
                          const int* __restrict__ dst, const float* __restrict__ dis,
                          float* __restrict__ out) {
  const long long ETOT = (long long)NEDGES + NNODES;
  int lane = threadIdx.x & 63;
  long long wid = (long long)(blockIdx.x * blockDim.x + threadIdx.x) >> 6;
  long long nw = ((long long)gridDim.x * blockDim.x) >> 6;
  for (long long e = wid; e < ETOT; e += nw) {
    int s, d;
    float nrm;
    if (e < NEDGES) {
      s = src[e];
      d = dst[e];
      nrm = dis[s] * dis[d];
    } else {
      s = (int)(e - NEDGES);
      d = s;
      float t = dis[s];
      nrm = t * t;
    }
    float v = h[(long long)s * FH + lane] * nrm;
    atomicAdd(&out[(long long)d * FH + lane], v);
  }
}

// ---------------- BN statistics: per-feature sum and sumsq ----------------

__global__ void k_bn_stats(const float* __restrict__ h, float* __restrict__ stats) {
  __shared__ float ls[2 * FH];
  int tid = threadIdx.x;
  if (tid < 2 * FH) ls[tid] = 0.0f;
  __syncthreads();
  int f = tid & (FH - 1);  // stride is a multiple of 64, so f is fixed per thread
  float s = 0.0f, ss = 0.0f;
  long long total = (long long)NNODES * FH;
  for (long long i = (long long)blockIdx.x * blockDim.x + tid; i < total;
       i += (long long)gridDim.x * blockDim.x) {
    float v = h[i];
    s += v;
    ss += v * v;
  }
  atomicAdd(&ls[f], s);
  atomicAdd(&ls[FH + f], ss);
  __syncthreads();
  if (tid < 2 * FH) atomicAdd(&stats[tid], ls[tid]);
}

__global__ void k_bn_finalize(const float* __restrict__ stats, const float* __restrict__ gamma,
                              const float* __restrict__ beta, float* __restrict__ scsh) {
  int f = threadIdx.x;
  if (f < FH) {
    float mean = stats[f] * (1.0f / NNODES);
    float var = stats[FH + f] * (1.0f / NNODES) - mean * mean;
    float s = gamma[f] * rsqrtf(var + EPSV);
    scsh[f] = s;
    scsh[FH + f] = beta[f] - mean * s;  // bias b cancels in training-mode BN
  }
}

// ---------------- pooling (applies BN2+ReLU on load) ----------------

__global__ void k_pool(const float* __restrict__ h, const int* __restrict__ batch,
                       const float* __restrict__ scsh, float* __restrict__ pooled,
                       float* __restrict__ cnt) {
  int lane = threadIdx.x & 63;
  int wid = (blockIdx.x * blockDim.x + threadIdx.x) >> 6;
  int nw = (gridDim.x * blockDim.x) >> 6;
  float sc = scsh[lane], sh = scsh[FH + lane];
  for (int n = wid; n < NNODES; n += nw) {
    int g = batch[n];
    float v = fmaf(h[(long long)n * FH + lane], sc, sh);
    v = fmaxf(v, 0.0f);
    atomicAdd(&pooled[g * FH + lane], v);
    if (lane == 0) atomicAdd(&cnt[g], 1.0f);
  }
}

// ---------------- final linear: out[G x 32] = (pooled/cnt) @ linW + linb -----

__global__ void k_final(const float* __restrict__ pooled, const float* __restrict__ cnt,
                        const float* __restrict__ linW, const float* __restrict__ linb,
                        float* __restrict__ out) {
  int t = blockIdx.x * blockDim.x + threadIdx.x;
  if (t >= NGRAPH * FOUT) return;
  int g = t / FOUT, o = t % FOUT;
  float inv = 1.0f / fmaxf(cnt[g], 1.0f);
  float acc = linb[o];
#pragma unroll
  for (int k = 0; k < FH; ++k) acc = fmaf(pooled[g * FH + k] * inv, linW[k * FOUT + o], acc);
  out[t] = acc;
}

extern "C" void kernel_launch(void* const* d_in, const int* in_sizes, int n_in,
                              void* d_out, int out_size, void* d_ws, size_t ws_size,
                              hipStream_t stream) {
  const float* x = (const float*)d_in[0];
  const int* edge_index = (const int*)d_in[1];
  const int* batch = (const int*)d_in[2];
  const float* W1 = (const float*)d_in[3];
  // d_in[4] = b1 (cancels in BN), d_in[6] = b2 (cancels in BN)
  const float* W2 = (const float*)d_in[5];
  const float* gamma = (const float*)d_in[7];
  const float* beta = (const float*)d_in[8];
  const float* linW = (const float*)d_in[9];
  const float* linb = (const float*)d_in[10];
  float* out = (float*)d_out;

  const int* esrc = edge_index;           // edge_index[0, :]
  const int* edst = edge_index + NEDGES;  // edge_index[1, :]

  // workspace layout
  float* bufA = (float*)d_ws;                  // N*64 (GEMM output)
  float* bufB = bufA + (long long)NNODES * FH; // N*64 (aggregation)
  float* dis = bufB + (long long)NNODES * FH;  // N (deg -> rsqrt(deg))
  float* stats1 = dis + NNODES;                // 128
  float* scsh1 = stats1 + 2 * FH;              // 128
  float* stats2 = scsh1 + 2 * FH;              // 128
  float* scsh2 = stats2 + 2 * FH;              // 128
  float* pooled = scsh2 + 2 * FH;              // G*64
  float* cnt = pooled + NGRAPH * FH;           // G

  const int BT = 256;
  const int gN = (NNODES + BT - 1) / BT;
  const int gE = (NEDGES + BT - 1) / BT;

  // zero all small accumulators in one shot (stats1..cnt are contiguous)
  hipMemsetAsync(stats1, 0, (size_t)(4 * 2 * FH + NGRAPH * FH + NGRAPH) * sizeof(float), stream);

  // normalization coefficients
  k_init_deg<<<gN, BT, 0, stream>>>(dis);
  k_deg_accum<<<gE, BT, 0, stream>>>(edst, dis);
  k_rsqrt<<<gN, BT, 0, stream>>>(dis);

  // layer 1
  k_gemm<FIN, false><<<gN, BT, 0, stream>>>(x, W1, nullptr, nullptr, bufA);
  hipMemsetAsync(bufB, 0, (size_t)NNODES * FH * sizeof(float), stream);
  k_scatter<<<2048, BT, 0, stream>>>(bufA, esrc, edst, dis, bufB);
  k_bn_stats<<<1024, BT, 0, stream>>>(bufB, stats1);
  k_bn_finalize<<<1, 64, 0, stream>>>(stats1, gamma, beta, scsh1);

  // layer 2 (BN1+ReLU fused into GEMM input load)
  k_gemm<FH, true><<<gN, BT, 0, stream>>>(bufB, W2, scsh1, scsh1 + FH, bufA);
  hipMemsetAsync(bufB, 0, (size_t)NNODES * FH * sizeof(float), stream);
  k_scatter<<<2048, BT, 0, stream>>>(bufA, esrc, edst, dis, bufB);
  k_bn_stats<<<1024, BT, 0, stream>>>(bufB, stats2);
  k_bn_finalize<<<1, 64, 0, stream>>>(stats2, gamma, beta, scsh2);

  // pooling (BN2+ReLU fused) + final linear
  k_pool<<<1024, BT, 0, stream>>>(bufB, batch, scsh2, pooled, cnt);
  k_final<<<(NGRAPH * FOUT + BT - 1) / BT, BT, 0, stream>>>(pooled, cnt, linW, linb, out);
}

// Round 2
// 1061.796 us; speedup vs baseline: 1.4581x; 1.4581x over previous
//
#include <hip/hip_runtime.h>

#define NNODES 100000
#define NEDGES 1600000
#define FIN 128
#define FH 64
#define FOUT 32
#define NGRAPH 128
#define EPSV 1e-5f

// ---------------- degree / normalization ----------------

__global__ void k_init_deg(float* __restrict__ deg) {
  int i = blockIdx.x * blockDim.x + threadIdx.x;
  if (i < NNODES) deg[i] = 1.0f;  // self-loop contributes 1
}

__global__ void k_deg_accum(const int* __restrict__ dst, float* __restrict__ deg) {
  int i = blockIdx.x * blockDim.x + threadIdx.x;
  if (i < NEDGES) atomicAdd(&deg[dst[i]], 1.0f);
}

__global__ void k_rsqrt(float* __restrict__ deg) {
  int i = blockIdx.x * blockDim.x + threadIdx.x;
  if (i < NNODES) deg[i] = rsqrtf(deg[i]);  // deg >= 1 always
}

// ---------------- skinny GEMM: out[N x 64] = act(A[N x K]) @ W[K x 64] -------
// One thread per row, 64 fp32 accumulators. W accesses are wave-uniform.
// If BN: input activation = relu(a * sc[k] + sh[k]) (fused BN+ReLU on load).

template <int K, bool BN>
__global__ void k_gemm(const float* __restrict__ A, const float* __restrict__ W,
                       const float* __restrict__ sc, const float* __restrict__ sh,
                       float* __restrict__ out) {
  int row = blockIdx.x * blockDim.x + threadIdx.x;
  if (row >= NNODES) return;
  float acc[FH];
#pragma unroll
  for (int j = 0; j < FH; ++j) acc[j] = 0.0f;
  const float* a = A + (long long)row * K;
  for (int k = 0; k < K; k += 4) {
    float4 x4 = *(const float4*)(a + k);
    float xs[4] = {x4.x, x4.y, x4.z, x4.w};
#pragma unroll
    for (int kk = 0; kk < 4; ++kk) {
      float xv = xs[kk];
      if (BN) {
        xv = fmaf(xv, sc[k + kk], sh[k + kk]);
        xv = fmaxf(xv, 0.0f);
      }
      const float* wr = W + (k + kk) * FH;
#pragma unroll
      for (int j = 0; j < FH; ++j) acc[j] = fmaf(xv, wr[j], acc[j]);
    }
  }
  float* o = out + (long long)row * FH;
#pragma unroll
  for (int j = 0; j < FH; j += 4) {
    float4 v = {acc[j], acc[j + 1], acc[j + 2], acc[j + 3]};
    *(float4*)(o + j) = v;
  }
}

// ---------------- message passing: out[dst] += h[src] * dis[src]*dis[dst] ----
// One wave per edge; lane = feature. Edges [0,E) are real, [E, E+N) self-loops.

__global__ void k_scatter(const float* __restrict__ h, const int* __restrict__ src,
                          const int* __restrict__ dst, const float* __restrict__ dis,
                          float* __restrict__ out) {
  const long long ETOT = (long long)NEDGES + NNODES;
  int lane = threadIdx.x & 63;
  long long wid = (long long)(blockIdx.x * blockDim.x + threadIdx.x) >> 6;
  long long nw = ((long long)gridDim.x * blockDim.x) >> 6;
  for (long long e = wid; e < ETOT; e += nw) {
    int s, d;
    float nrm;
    if (e < NEDGES) {
      s = src[e];
      d = dst[e];
      nrm = dis[s] * dis[d];
    } else {
      s = (int)(e - NEDGES);
      d = s;
      float t = dis[s];
      nrm = t * t;
    }
    float v = h[(long long)s * FH + lane] * nrm;
    atomicAdd(&out[(long long)d * FH + lane], v);
  }
}

// ---------------- BN statistics: per-feature sum and sumsq ----------------

__global__ void k_bn_stats(const float* __restrict__ h, float* __restrict__ stats) {
  __shared__ float ls[2 * FH];
  int tid = threadIdx.x;
  if (tid < 2 * FH) ls[tid] = 0.0f;
  __syncthreads();
  int f = tid & (FH - 1);  // stride is a multiple of 64, so f is fixed per thread
  float s = 0.0f, ss = 0.0f;
  long long total = (long long)NNODES * FH;
  for (long long i = (long long)blockIdx.x * blockDim.x + tid; i < total;
       i += (long long)gridDim.x * blockDim.x) {
    float v = h[i];
    s += v;
    ss += v * v;
  }
  atomicAdd(&ls[f], s);
  atomicAdd(&ls[FH + f], ss);
  __syncthreads();
  if (tid < 2 * FH) atomicAdd(&stats[tid], ls[tid]);
}

__global__ void k_bn_finalize(const float* __restrict__ stats, const float* __restrict__ gamma,
                              const float* __restrict__ beta, float* __restrict__ scsh) {
  int f = threadIdx.x;
  if (f < FH) {
    float mean = stats[f] * (1.0f / NNODES);
    float var = stats[FH + f] * (1.0f / NNODES) - mean * mean;
    float s = gamma[f] * rsqrtf(var + EPSV);
    scsh[f] = s;
    scsh[FH + f] = beta[f] - mean * s;  // bias b cancels in training-mode BN
  }
}

// ---------------- pooling (applies BN2+ReLU on load) ----------------
// batch is SORTED -> segment-reduce per wave-chunk in registers, flush one
// atomic per segment boundary instead of one per node (6.4M -> ~74K atomics).

#define POOL_WAVES 1024

__global__ void k_pool(const float* __restrict__ h, const int* __restrict__ batch,
                       const float* __restrict__ scsh, float* __restrict__ pooled,
                       float* __restrict__ cnt) {
  const int CHUNK = (NNODES + POOL_WAVES - 1) / POOL_WAVES;
  int lane = threadIdx.x & 63;
  int wid = (blockIdx.x * blockDim.x + threadIdx.x) >> 6;
  int start = wid * CHUNK;
  if (start >= NNODES) return;
  int end = min(start + CHUNK, NNODES);
  float sc = scsh[lane], sh = scsh[FH + lane];
  int cur = batch[start];  // wave-uniform
  float acc = 0.0f;
  int cl = 0;
  for (int n = start; n < end; ++n) {
    int g = batch[n];
    if (g != cur) {  // uniform branch (batch value identical across lanes)
      atomicAdd(&pooled[cur * FH + lane], acc);
      if (lane == 0) atomicAdd(&cnt[cur], (float)cl);
      acc = 0.0f;
      cl = 0;
      cur = g;
    }
    float v = fmaf(h[(long long)n * FH + lane], sc, sh);
    acc += fmaxf(v, 0.0f);
    ++cl;
  }
  atomicAdd(&pooled[cur * FH + lane], acc);
  if (lane == 0) atomicAdd(&cnt[cur], (float)cl);
}

// ---------------- final linear: out[G x 32] = (pooled/cnt) @ linW + linb -----

__global__ void k_final(const float* __restrict__ pooled, const float* __restrict__ cnt,
                        const float* __restrict__ linW, const float* __restrict__ linb,
                        float* __restrict__ out) {
  int t = blockIdx.x * blockDim.x + threadIdx.x;
  if (t >= NGRAPH * FOUT) return;
  int g = t / FOUT, o = t % FOUT;
  float inv = 1.0f / fmaxf(cnt[g], 1.0f);
  float acc = linb[o];
#pragma unroll
  for (int k = 0; k < FH; ++k) acc = fmaf(pooled[g * FH + k] * inv, linW[k * FOUT + o], acc);
  out[t] = acc;
}

extern "C" void kernel_launch(void* const* d_in, const int* in_sizes, int n_in,
                              void* d_out, int out_size, void* d_ws, size_t ws_size,
                              hipStream_t stream) {
  const float* x = (const float*)d_in[0];
  const int* edge_index = (const int*)d_in[1];
  const int* batch = (const int*)d_in[2];
  const float* W1 = (const float*)d_in[3];
  // d_in[4] = b1 (cancels in BN), d_in[6] = b2 (cancels in BN)
  const float* W2 = (const float*)d_in[5];
  const float* gamma = (const float*)d_in[7];
  const float* beta = (const float*)d_in[8];
  const float* linW = (const float*)d_in[9];
  const float* linb = (const float*)d_in[10];
  float* out = (float*)d_out;

  const int* esrc = edge_index;           // edge_index[0, :]
  const int* edst = edge_index + NEDGES;  // edge_index[1, :]

  // workspace layout
  float* bufA = (float*)d_ws;                  // N*64 (GEMM output)
  float* bufB = bufA + (long long)NNODES * FH; // N*64 (aggregation)
  float* dis = bufB + (long long)NNODES * FH;  // N (deg -> rsqrt(deg))
  float* stats1 = dis + NNODES;                // 128
  float* scsh1 = stats1 + 2 * FH;              // 128
  float* stats2 = scsh1 + 2 * FH;              // 128
  float* scsh2 = stats2 + 2 * FH;              // 128
  float* pooled = scsh2 + 2 * FH;              // G*64
  float* cnt = pooled + NGRAPH * FH;           // G

  const int BT = 256;
  const int gN = (NNODES + BT - 1) / BT;
  const int gE = (NEDGES + BT - 1) / BT;

  // zero all small accumulators in one shot (stats1..cnt are contiguous)
  hipMemsetAsync(stats1, 0, (size_t)(4 * 2 * FH + NGRAPH * FH + NGRAPH) * sizeof(float), stream);

  // normalization coefficients
  k_init_deg<<<gN, BT, 0, stream>>>(dis);
  k_deg_accum<<<gE, BT, 0, stream>>>(edst, dis);
  k_rsqrt<<<gN, BT, 0, stream>>>(dis);

  // layer 1
  k_gemm<FIN, false><<<gN, BT, 0, stream>>>(x, W1, nullptr, nullptr, bufA);
  hipMemsetAsync(bufB, 0, (size_t)NNODES * FH * sizeof(float), stream);
  k_scatter<<<2048, BT, 0, stream>>>(bufA, esrc, edst, dis, bufB);
  k_bn_stats<<<1024, BT, 0, stream>>>(bufB, stats1);
  k_bn_finalize<<<1, 64, 0, stream>>>(stats1, gamma, beta, scsh1);

  // layer 2 (BN1+ReLU fused into GEMM input load)
  k_gemm<FH, true><<<gN, BT, 0, stream>>>(bufB, W2, scsh1, scsh1 + FH, bufA);
  hipMemsetAsync(bufB, 0, (size_t)NNODES * FH * sizeof(float), stream);
  k_scatter<<<2048, BT, 0, stream>>>(bufA, esrc, edst, dis, bufB);
  k_bn_stats<<<1024, BT, 0, stream>>>(bufB, stats2);
  k_bn_finalize<<<1, 64, 0, stream>>>(stats2, gamma, beta, scsh2);

  // pooling (BN2+ReLU fused) + final linear
  k_pool<<<POOL_WAVES * 64 / BT, BT, 0, stream>>>(bufB, batch, scsh2, pooled, cnt);
  k_final<<<(NGRAPH * FOUT + BT - 1) / BT, BT, 0, stream>>>(pooled, cnt, linW, linb, out);
}

// Round 3
// 717.250 us; speedup vs baseline: 2.1585x; 1.4804x over previous
//
#include <hip/hip_runtime.h>

#define NNODES 100000
#define NEDGES 1600000
#define FIN 128
#define FH 64
#define FOUT 32
#define NGRAPH 128
#define EPSV 1e-5f

#define SCAN_BT 256
#define NBLK ((NNODES + SCAN_BT - 1) / SCAN_BT)  // 391

// ---------------- degree / normalization ----------------

__global__ void k_init_deg(float* __restrict__ deg) {
  int i = blockIdx.x * blockDim.x + threadIdx.x;
  if (i < NNODES) deg[i] = 1.0f;  // self-loop contributes 1
}

__global__ void k_deg_accum(const int* __restrict__ dst, float* __restrict__ deg) {
  int i = blockIdx.x * blockDim.x + threadIdx.x;
  if (i < NEDGES) atomicAdd(&deg[dst[i]], 1.0f);
}

__global__ void k_rsqrt(float* __restrict__ deg) {
  int i = blockIdx.x * blockDim.x + threadIdx.x;
  if (i < NNODES) deg[i] = rsqrtf(deg[i]);  // deg >= 1 always
}

// ---------------- CSR build: hierarchical exclusive scan of in-degrees ------
// counts[d] = (int)deg[d] - 1  (deg still holds raw degree incl. self-loop)

__global__ void k_blocksum(const float* __restrict__ deg, int* __restrict__ bsum) {
  __shared__ int ls[SCAN_BT];
  int b = blockIdx.x, t = threadIdx.x;
  int i = b * SCAN_BT + t;
  ls[t] = (i < NNODES) ? (int)deg[i] - 1 : 0;
  __syncthreads();
  for (int s = SCAN_BT / 2; s > 0; s >>= 1) {
    if (t < s) ls[t] += ls[t + s];
    __syncthreads();
  }
  if (t == 0) bsum[b] = ls[0];
}

__global__ void k_scan_bsums(const int* __restrict__ bsum, int* __restrict__ boff) {
  // one block of 512 threads; NBLK <= 512
  __shared__ int ls[512];
  int t = threadIdx.x;
  int v = (t < NBLK) ? bsum[t] : 0;
  ls[t] = v;
  __syncthreads();
  for (int s = 1; s < 512; s <<= 1) {
    int add = (t >= s) ? ls[t - s] : 0;
    __syncthreads();
    ls[t] += add;
    __syncthreads();
  }
  if (t < NBLK) boff[t] = ls[t] - v;  // exclusive
}

__global__ void k_scan_final(const float* __restrict__ deg, const int* __restrict__ boff,
                             int* __restrict__ off) {
  __shared__ int ls[SCAN_BT];
  int b = blockIdx.x, t = threadIdx.x;
  int i = b * SCAN_BT + t;
  int v = (i < NNODES) ? (int)deg[i] - 1 : 0;
  ls[t] = v;
  __syncthreads();
  for (int s = 1; s < SCAN_BT; s <<= 1) {
    int add = (t >= s) ? ls[t - s] : 0;
    __syncthreads();
    ls[t] += add;
    __syncthreads();
  }
  if (i < NNODES) off[i] = boff[b] + ls[t] - v;  // exclusive offset
  if (i == NNODES - 1) off[NNODES] = boff[b] + ls[t];
}

__global__ void k_fill(const int* __restrict__ src, const int* __restrict__ dst,
                       const int* __restrict__ off, int* __restrict__ cursor,
                       int* __restrict__ csr) {
  int i = blockIdx.x * blockDim.x + threadIdx.x;
  if (i < NEDGES) {
    int d = dst[i];
    int p = atomicAdd(&cursor[d], 1);
    csr[off[d] + p] = src[i];
  }
}

// ---------------- skinny GEMM: out[N x 64] = act(A[N x K]) @ W[K x 64] -------
// One thread per row, 64 fp32 accumulators. Epilogue scales by dis[row] so the
// gather kernel needs no per-edge dis loads (symmetric norm folded in).

template <int K, bool BN>
__global__ void k_gemm(const float* __restrict__ A, const float* __restrict__ W,
                       const float* __restrict__ sc, const float* __restrict__ sh,
                       const float* __restrict__ dis, float* __restrict__ out) {
  int row = blockIdx.x * blockDim.x + threadIdx.x;
  if (row >= NNODES) return;
  float acc[FH];
#pragma unroll
  for (int j = 0; j < FH; ++j) acc[j] = 0.0f;
  const float* a = A + (long long)row * K;
  for (int k = 0; k < K; k += 4) {
    float4 x4 = *(const float4*)(a + k);
    float xs[4] = {x4.x, x4.y, x4.z, x4.w};
#pragma unroll
    for (int kk = 0; kk < 4; ++kk) {
      float xv = xs[kk];
      if (BN) {
        xv = fmaf(xv, sc[k + kk], sh[k + kk]);
        xv = fmaxf(xv, 0.0f);
      }
      const float* wr = W + (k + kk) * FH;
#pragma unroll
      for (int j = 0; j < FH; ++j) acc[j] = fmaf(xv, wr[j], acc[j]);
    }
  }
  float d = dis[row];
  float* o = out + (long long)row * FH;
#pragma unroll
  for (int j = 0; j < FH; j += 4) {
    float4 v = {acc[j] * d, acc[j + 1] * d, acc[j + 2] * d, acc[j + 3] * d};
    *(float4*)(o + j) = v;
  }
}

// ---------------- aggregation: out[d] = dis[d] * (hs[d] + sum hs[csr]) ------
// One wave per dst node, register accumulation, no atomics on the feature
// matrix. BN statistics fused into the epilogue (per-block LDS + one atomic).

__global__ void k_gather(const float* __restrict__ hs, const int* __restrict__ csr,
                         const int* __restrict__ off, const float* __restrict__ dis,
                         float* __restrict__ out, float* __restrict__ stats) {
  __shared__ float ls[2 * FH];
  int tid = threadIdx.x;
  if (tid < 2 * FH) ls[tid] = 0.0f;
  __syncthreads();
  int lane = tid & 63;
  int wid = (blockIdx.x * blockDim.x + tid) >> 6;
  int nw = (gridDim.x * blockDim.x) >> 6;
  float s1 = 0.0f, s2 = 0.0f;
  for (int d = wid; d < NNODES; d += nw) {
    float acc = hs[(long long)d * FH + lane];  // self-loop term
    int b = off[d], e = off[d + 1];
    for (int k = b; k < e; ++k) {
      int s = csr[k];  // wave-uniform
      acc += hs[(long long)s * FH + lane];
    }
    float o = acc * dis[d];
    out[(long long)d * FH + lane] = o;
    s1 += o;
    s2 += o * o;
  }
  atomicAdd(&ls[lane], s1);
  atomicAdd(&ls[FH + lane], s2);
  __syncthreads();
  if (tid < 2 * FH) atomicAdd(&stats[tid], ls[tid]);
}

__global__ void k_bn_finalize(const float* __restrict__ stats, const float* __restrict__ gamma,
                              const float* __restrict__ beta, float* __restrict__ scsh) {
  int f = threadIdx.x;
  if (f < FH) {
    float mean = stats[f] * (1.0f / NNODES);
    float var = stats[FH + f] * (1.0f / NNODES) - mean * mean;
    float s = gamma[f] * rsqrtf(var + EPSV);
    scsh[f] = s;
    scsh[FH + f] = beta[f] - mean * s;  // bias b cancels in training-mode BN
  }
}

// ---------------- pooling (applies BN2+ReLU on load) ----------------
// batch is SORTED -> segment-reduce per wave-chunk in registers.

#define POOL_WAVES 1024

__global__ void k_pool(const float* __restrict__ h, const int* __restrict__ batch,
                       const float* __restrict__ scsh, float* __restrict__ pooled,
                       float* __restrict__ cnt) {
  const int CHUNK = (NNODES + POOL_WAVES - 1) / POOL_WAVES;
  int lane = threadIdx.x & 63;
  int wid = (blockIdx.x * blockDim.x + threadIdx.x) >> 6;
  int start = wid * CHUNK;
  if (start >= NNODES) return;
  int end = min(start + CHUNK, NNODES);
  float sc = scsh[lane], sh = scsh[FH + lane];
  int cur = batch[start];  // wave-uniform
  float acc = 0.0f;
  int cl = 0;
  for (int n = start; n < end; ++n) {
    int g = batch[n];
    if (g != cur) {  // uniform branch
      atomicAdd(&pooled[cur * FH + lane], acc);
      if (lane == 0) atomicAdd(&cnt[cur], (float)cl);
      acc = 0.0f;
      cl = 0;
      cur = g;
    }
    float v = fmaf(h[(long long)n * FH + lane], sc, sh);
    acc += fmaxf(v, 0.0f);
    ++cl;
  }
  atomicAdd(&pooled[cur * FH + lane], acc);
  if (lane == 0) atomicAdd(&cnt[cur], (float)cl);
}

// ---------------- final linear: out[G x 32] = (pooled/cnt) @ linW + linb -----

__global__ void k_final(const float* __restrict__ pooled, const float* __restrict__ cnt,
                        const float* __restrict__ linW, const float* __restrict__ linb,
                        float* __restrict__ out) {
  int t = blockIdx.x * blockDim.x + threadIdx.x;
  if (t >= NGRAPH * FOUT) return;
  int g = t / FOUT, o = t % FOUT;
  float inv = 1.0f / fmaxf(cnt[g], 1.0f);
  float acc = linb[o];
#pragma unroll
  for (int k = 0; k < FH; ++k) acc = fmaf(pooled[g * FH + k] * inv, linW[k * FOUT + o], acc);
  out[t] = acc;
}

extern "C" void kernel_launch(void* const* d_in, const int* in_sizes, int n_in,
                              void* d_out, int out_size, void* d_ws, size_t ws_size,
                              hipStream_t stream) {
  const float* x = (const float*)d_in[0];
  const int* edge_index = (const int*)d_in[1];
  const int* batch = (const int*)d_in[2];
  const float* W1 = (const float*)d_in[3];
  // d_in[4] = b1 (cancels in BN), d_in[6] = b2 (cancels in BN)
  const float* W2 = (const float*)d_in[5];
  const float* gamma = (const float*)d_in[7];
  const float* beta = (const float*)d_in[8];
  const float* linW = (const float*)d_in[9];
  const float* linb = (const float*)d_in[10];
  float* out = (float*)d_out;

  const int* esrc = edge_index;           // edge_index[0, :]
  const int* edst = edge_index + NEDGES;  // edge_index[1, :]

  // workspace layout
  float* bufA = (float*)d_ws;                   // N*64 (GEMM output, dis-scaled)
  float* bufB = bufA + (long long)NNODES * FH;  // N*64 (aggregation output)
  float* dis = bufB + (long long)NNODES * FH;   // N (deg -> rsqrt(deg))
  int* off = (int*)(dis + NNODES);              // N+1
  int* csr = off + (NNODES + 1);                // E
  int* bsum = csr + NEDGES;                     // NBLK
  int* boff = bsum + NBLK;                      // NBLK
  int* cursor = boff + NBLK;                    // N   --- zeroed region start
  float* stats1 = (float*)(cursor + NNODES);    // 128
  float* scsh1 = stats1 + 2 * FH;               // 128
  float* stats2 = scsh1 + 2 * FH;               // 128
  float* scsh2 = stats2 + 2 * FH;               // 128
  float* pooled = scsh2 + 2 * FH;               // G*64
  float* cnt = pooled + NGRAPH * FH;            // G   --- zeroed region end

  const int BT = 256;
  const int gN = (NNODES + BT - 1) / BT;
  const int gE = (NEDGES + BT - 1) / BT;

  // zero cursor + stats + pooled + cnt in one shot (contiguous)
  hipMemsetAsync(cursor, 0,
                 (size_t)(NNODES + 4 * 2 * FH + NGRAPH * FH + NGRAPH) * sizeof(float), stream);

  // degrees (raw), CSR offsets, then rsqrt in place, then fill
  k_init_deg<<<gN, BT, 0, stream>>>(dis);
  k_deg_accum<<<gE, BT, 0, stream>>>(edst, dis);
  k_blocksum<<<NBLK, SCAN_BT, 0, stream>>>(dis, bsum);
  k_scan_bsums<<<1, 512, 0, stream>>>(bsum, boff);
  k_scan_final<<<NBLK, SCAN_BT, 0, stream>>>(dis, boff, off);
  k_rsqrt<<<gN, BT, 0, stream>>>(dis);
  k_fill<<<gE, BT, 0, stream>>>(esrc, edst, off, cursor, csr);

  // layer 1
  k_gemm<FIN, false><<<gN, BT, 0, stream>>>(x, W1, nullptr, nullptr, dis, bufA);
  k_gather<<<2048, BT, 0, stream>>>(bufA, csr, off, dis, bufB, stats1);
  k_bn_finalize<<<1, 64, 0, stream>>>(stats1, gamma, beta, scsh1);

  // layer 2 (BN1+ReLU fused into GEMM input load)
  k_gemm<FH, true><<<gN, BT, 0, stream>>>(bufB, W2, scsh1, scsh1 + FH, dis, bufA);
  k_gather<<<2048, BT, 0, stream>>>(bufA, csr, off, dis, bufB, stats2);
  k_bn_finalize<<<1, 64, 0, stream>>>(stats2, gamma, beta, scsh2);

  // pooling (BN2+ReLU fused) + final linear
  k_pool<<<POOL_WAVES * 64 / BT, BT, 0, stream>>>(bufB, batch, scsh2, pooled, cnt);
  k_final<<<(NGRAPH * FOUT + BT - 1) / BT, BT, 0, stream>>>(pooled, cnt, linW, linb, out);
}